// Round 1
// baseline (152.010 us; speedup 1.0000x reference)
//
#include <hip/hip_runtime.h>
#include <math.h>

#define NN 4096
#define KTOP 20
#define EPSF 1e-6f

// ---------------- block reduction helpers (256 threads = 4 waves) ----------------
__device__ __forceinline__ float block_rmax(float v, volatile float* red) {
#pragma unroll
  for (int o = 1; o < 64; o <<= 1) v = fmaxf(v, __shfl_xor(v, o, 64));
  __syncthreads();
  if ((threadIdx.x & 63) == 0) red[threadIdx.x >> 6] = v;
  __syncthreads();
  return fmaxf(fmaxf(red[0], red[1]), fmaxf(red[2], red[3]));
}
__device__ __forceinline__ float block_rsumf(float v, volatile float* red) {
#pragma unroll
  for (int o = 1; o < 64; o <<= 1) v += __shfl_xor(v, o, 64);
  __syncthreads();
  if ((threadIdx.x & 63) == 0) red[threadIdx.x >> 6] = v;
  __syncthreads();
  return red[0] + red[1] + red[2] + red[3];
}
__device__ __forceinline__ int block_rsumi(int v, volatile int* red) {
#pragma unroll
  for (int o = 1; o < 64; o <<= 1) v += __shfl_xor(v, o, 64);
  __syncthreads();
  if ((threadIdx.x & 63) == 0) red[threadIdx.x >> 6] = v;
  __syncthreads();
  return red[0] + red[1] + red[2] + red[3];
}

// ---------------- K1: feat (normalized), sev, impacted count ----------------
__global__ void k_prep(const float* __restrict__ xh, const float* __restrict__ ev,
                       float2* __restrict__ featn, float* __restrict__ sev,
                       int* __restrict__ cnt) {
  int i = blockIdx.x * 256 + threadIdx.x;
  float sx = 0.f, sy = 0.f, se = 0.f;
  const float2* xh2 = (const float2*)xh;
  for (int bt = 0; bt < 192; ++bt) {
    float2 v = xh2[bt * NN + i];
    sx += v.x; sy += v.y;
    se += ev[bt * NN + i];
  }
  sx *= (1.f / 192.f); sy *= (1.f / 192.f); se *= (1.f / 192.f);
  float nrm = sqrtf(sx * sx + sy * sy) + EPSF;
  featn[i] = make_float2(sx / nrm, sy / nrm);
  sev[i] = se;
  unsigned long long m = __ballot(se > 0.f);
  if ((threadIdx.x & 63) == 0) atomicAdd(cnt, (int)__popcll(m));
}

// ---------------- K2: per-row fused stats + A_dyn + exact top-k ----------------
__global__ __launch_bounds__(256) void k_row(
    const float* __restrict__ base_adj, const float2* __restrict__ featn,
    const float* __restrict__ sev, const float* __restrict__ nv1,
    const float* __restrict__ nv2, const float* __restrict__ alpha,
    const int* __restrict__ cnt, int* __restrict__ kidx,
    float* __restrict__ kval, float* __restrict__ deg) {
  const int i = blockIdx.x;
  const int tid = threadIdx.x;

  __shared__ float redf[4];
  __shared__ int redi[4];
  __shared__ int eq_js[64];
  __shared__ int eq_cnt, slot, keep_n;

  // row constants
  float2 fi = featn[i];
  float sevi = sev[i];
  float v1[10];
#pragma unroll
  for (int d = 0; d < 10; ++d) v1[d] = nv1[i * 10 + d];
  float a0 = alpha[0];
  float gamma = 1.f / (1.f + __expf(-a0));
  const float esc = sevi * 0.6065306597f;  // exp(-0.5)

  float hdot[16], adot[16], basev[16];
  float hmax = 0.f, emax = 0.f, amax = 0.f;

#pragma unroll
  for (int c = 0; c < 16; ++c) {
    int j = c * 256 + tid;
    float b = base_adj[(size_t)i * NN + j];
    float2 fj = featn[j];
    float h = fmaxf(fi.x * fj.x + fi.y * fj.y, 0.f);
    float a = 0.f;
#pragma unroll
    for (int d = 0; d < 10; ++d) a += v1[d] * nv2[d * NN + j];
    a = fmaxf(a, 0.f);
    float e = fmaxf(esc * b, 0.f);
    hdot[c] = h; adot[c] = a; basev[c] = b;
    hmax = fmaxf(hmax, h);
    amax = fmaxf(amax, a);
    emax = fmaxf(emax, e);
  }
  hmax = block_rmax(hmax, redf);
  amax = block_rmax(amax, redf);
  emax = block_rmax(emax, redf);

  float hs = 0.f, as = 0.f, es = 0.f;
#pragma unroll
  for (int c = 0; c < 16; ++c) {
    float he = __expf(hdot[c] - hmax); hdot[c] = he; hs += he;
    float ae = __expf(adot[c] - amax); adot[c] = ae; as += ae;
    float ee = __expf(fmaxf(esc * basev[c], 0.f) - emax); es += ee;
  }
  hs = block_rsumf(hs, redf);
  as = block_rsumf(as, redf);
  es = block_rsumf(es, redf);

  float eflag = (*cnt > 0) ? 1.f : 0.f;
  float w_h = 0.5f * gamma / hs;
  float w_e = 0.5f * (1.f - gamma) * eflag / es;
  float w_a = 0.5f / as;

#pragma unroll
  for (int c = 0; c < 16; ++c) {
    float ee = __expf(fmaxf(esc * basev[c], 0.f) - emax);
    float v = w_h * hdot[c] + w_e * ee + 0.5f * basev[c] + w_a * adot[c];
    hdot[c] = v;  // reuse as A_dyn values (all strictly > 0)
  }

  // ---- exact k-th largest via binary search over positive-float bit patterns ----
  unsigned cur = 0u;
  for (int b = 30; b >= 0; --b) {
    float t = __uint_as_float(cur | (1u << b));
    int lc = 0;
#pragma unroll
    for (int c = 0; c < 16; ++c) lc += (hdot[c] >= t) ? 1 : 0;
    int tot = block_rsumi(lc, redi);
    if (tot >= KTOP) cur |= (1u << b);
  }
  const float T = __uint_as_float(cur);

  int lc = 0;
#pragma unroll
  for (int c = 0; c < 16; ++c) lc += (hdot[c] > T) ? 1 : 0;
  int cgt = block_rsumi(lc, redi);
  int need = KTOP - cgt;

  if (tid == 0) { eq_cnt = 0; slot = 0; }
  __syncthreads();
#pragma unroll
  for (int c = 0; c < 16; ++c) {
    if (hdot[c] == T) {
      int p = atomicAdd(&eq_cnt, 1);
      if (p < 64) eq_js[p] = c * 256 + tid;
    }
  }
  __syncthreads();
  if (tid == 0) {
    int m = eq_cnt < 64 ? eq_cnt : 64;
    int nk = need < m ? need : m;
    // partial selection sort: smallest `nk` indices to front (stable tie-break)
    for (int s = 0; s < nk; ++s) {
      int best = s;
      for (int t2 = s + 1; t2 < m; ++t2)
        if (eq_js[t2] < eq_js[best]) best = t2;
      int tmp = eq_js[s]; eq_js[s] = eq_js[best]; eq_js[best] = tmp;
    }
    keep_n = nk;
  }
  __syncthreads();
  int kn = keep_n;

  float ksum = 0.f;
#pragma unroll
  for (int c = 0; c < 16; ++c) {
    int j = c * 256 + tid;
    float v = hdot[c];
    bool keep = (v > T);
    if (!keep && v == T) {
      for (int s = 0; s < kn; ++s)
        if (eq_js[s] == j) { keep = true; break; }
    }
    if (keep) {
      int s = atomicAdd(&slot, 1);
      kidx[i * KTOP + s] = j;
      kval[i * KTOP + s] = v;
      ksum += v;
    }
  }
  ksum = block_rsumf(ksum, redf);
  if (tid == 0) deg[i] = ksum + 1.f;
}

// ---------------- K3: d^{-1/2} ----------------
__global__ void k_dinv(const float* __restrict__ deg, float* __restrict__ dinv) {
  int i = blockIdx.x * 256 + threadIdx.x;
  dinv[i] = 1.f / sqrtf(deg[i] + EPSF);
}

// ---------------- K4: write normalized sparse output ----------------
__global__ __launch_bounds__(256) void k_write(
    const int* __restrict__ kidx, const float* __restrict__ kval,
    const float* __restrict__ dinv, float* __restrict__ out) {
  const int i = blockIdx.x;
  const int tid = threadIdx.x;
  __shared__ float row[NN];
  float4* r4 = (float4*)row;
#pragma unroll
  for (int c = 0; c < 4; ++c) r4[c * 256 + tid] = make_float4(0.f, 0.f, 0.f, 0.f);
  __syncthreads();
  if (tid < KTOP) {
    int j = kidx[i * KTOP + tid];
    row[j] = kval[i * KTOP + tid];
  }
  __syncthreads();
  float di = dinv[i];
  const float4* dv4 = (const float4*)dinv;
  float4* o4 = (float4*)out;
#pragma unroll
  for (int c = 0; c < 4; ++c) {
    int j4 = c * 256 + tid;
    float4 rv = r4[j4];
    float4 dv = dv4[j4];
    int jb = j4 * 4;
    float4 o;
    o.x = di * (rv.x + ((jb + 0) == i ? 1.f : 0.f)) * dv.x;
    o.y = di * (rv.y + ((jb + 1) == i ? 1.f : 0.f)) * dv.y;
    o.z = di * (rv.z + ((jb + 2) == i ? 1.f : 0.f)) * dv.z;
    o.w = di * (rv.w + ((jb + 3) == i ? 1.f : 0.f)) * dv.w;
    o4[(size_t)i * (NN / 4) + j4] = o;
  }
}

extern "C" void kernel_launch(void* const* d_in, const int* in_sizes, int n_in,
                              void* d_out, int out_size, void* d_ws, size_t ws_size,
                              hipStream_t stream) {
  const float* xh    = (const float*)d_in[0];
  const float* ev    = (const float*)d_in[1];
  const float* base  = (const float*)d_in[2];
  const float* nv1   = (const float*)d_in[3];
  const float* nv2   = (const float*)d_in[4];
  const float* alpha = (const float*)d_in[5];
  float* out = (float*)d_out;

  char* ws = (char*)d_ws;
  int*    cnt   = (int*)ws;                                   // 4 B
  float2* featn = (float2*)(ws + 256);                        // 32 KB
  float*  sev   = (float*)(ws + 256 + 32768);                 // 16 KB
  float*  deg   = (float*)(ws + 256 + 32768 + 16384);         // 16 KB
  float*  dinv  = (float*)(ws + 256 + 32768 + 32768);         // 16 KB
  int*    kidx  = (int*)(ws + 256 + 32768 + 49152);           // 320 KB
  float*  kval  = (float*)(ws + 256 + 32768 + 49152 + NN * KTOP * 4);  // 320 KB

  hipMemsetAsync(cnt, 0, 4, stream);
  k_prep<<<NN / 256, 256, 0, stream>>>(xh, ev, featn, sev, cnt);
  k_row<<<NN, 256, 0, stream>>>(base, featn, sev, nv1, nv2, alpha, cnt, kidx, kval, deg);
  k_dinv<<<NN / 256, 256, 0, stream>>>(deg, dinv);
  k_write<<<NN, 256, 0, stream>>>(kidx, kval, dinv, out);
}

// Round 2
// 99.667 us; speedup vs baseline: 1.5252x; 1.5252x over previous
//
#include <hip/hip_runtime.h>
#include <math.h>

#define NN 4096
#define KTOP 20
#define EPSF 1e-6f

// ---------------- block sum over 256 threads (4 waves) ----------------
__device__ __forceinline__ float block_rsumf(float v, volatile float* red) {
#pragma unroll
  for (int o = 1; o < 64; o <<= 1) v += __shfl_xor(v, o, 64);
  __syncthreads();
  if ((threadIdx.x & 63) == 0) red[threadIdx.x >> 6] = v;
  __syncthreads();
  return red[0] + red[1] + red[2] + red[3];
}

// ---------------- K1: feat (normalized), sev, impacted count, nv2 transpose ----------------
__global__ void k_prep(const float* __restrict__ xh, const float* __restrict__ ev,
                       const float* __restrict__ nv2,
                       float2* __restrict__ featn, float* __restrict__ sev,
                       float* __restrict__ nv2t, int* __restrict__ cnt) {
  int i = blockIdx.x * 256 + threadIdx.x;
  float sx = 0.f, sy = 0.f, se = 0.f;
  const float2* xh2 = (const float2*)xh;
  for (int bt = 0; bt < 192; ++bt) {
    float2 v = xh2[bt * NN + i];
    sx += v.x; sy += v.y;
    se += ev[bt * NN + i];
  }
  sx *= (1.f / 192.f); sy *= (1.f / 192.f); se *= (1.f / 192.f);
  float nrm = sqrtf(sx * sx + sy * sy) + EPSF;
  featn[i] = make_float2(sx / nrm, sy / nrm);
  sev[i] = se;
#pragma unroll
  for (int d = 0; d < 10; ++d) nv2t[i * 10 + d] = nv2[d * NN + i];
  unsigned long long m = __ballot(se > 0.f);
  if ((threadIdx.x & 63) == 0) atomicAdd(cnt, (int)__popcll(m));
}

// ---------------- K2: per-row fused A_dyn + exact top-k via MSD radix select ----------------
__global__ __launch_bounds__(256) void k_row(
    const float* __restrict__ base_adj, const float2* __restrict__ featn,
    const float* __restrict__ sev, const float* __restrict__ nv1,
    const float* __restrict__ nv2t, const float* __restrict__ alpha,
    const int* __restrict__ cnt, int* __restrict__ kidx,
    float* __restrict__ kval, float* __restrict__ deg) {
  const int i = blockIdx.x;
  const int tid = threadIdx.x;
  const int lane = tid & 63, wv = tid >> 6;

  __shared__ int hist[2048];
  __shared__ float candV[64];
  __shared__ int candJ[64];
  __shared__ float redf[12];
  __shared__ int wtot[4];
  __shared__ int sB, sAbv, sNC, ccnt, slotc;
  __shared__ float sCsum;

#pragma unroll
  for (int z = 0; z < 8; ++z) hist[z * 256 + tid] = 0;
  if (tid == 0) slotc = 0;

  // ---- row constants ----
  float2 fi = featn[i];
  float sevi = sev[i];
  float v1[10];
#pragma unroll
  for (int d = 0; d < 10; ++d) v1[d] = nv1[i * 10 + d];
  float gamma = 1.f / (1.f + __expf(-alpha[0]));
  const float esc = sevi * 0.6065306597f;  // sev_i * exp(-0.5)

  // ---- pass 1: logits -> exp (no max-subtraction needed; args bounded) ----
  float he[16], ae[16], bb[16];
  float hs = 0.f, as = 0.f, es = 0.f;
#pragma unroll
  for (int c = 0; c < 16; ++c) {
    int j = c * 256 + tid;
    float b = base_adj[(size_t)i * NN + j];
    float2 fj = featn[j];
    float h = fmaxf(fi.x * fj.x + fi.y * fj.y, 0.f);
    const float2* nj = (const float2*)(nv2t + j * 10);
    float a = 0.f;
#pragma unroll
    for (int d = 0; d < 5; ++d) {
      float2 w = nj[d];
      a += v1[2 * d] * w.x + v1[2 * d + 1] * w.y;
    }
    a = fmaxf(a, 0.f);
    float hev = __expf(h); he[c] = hev; hs += hev;
    float aev = __expf(a); ae[c] = aev; as += aev;
    es += __expf(fmaxf(esc * b, 0.f));
    bb[c] = b;
  }
  // ---- fused 3-way block reduction (one barrier round) ----
#pragma unroll
  for (int o = 1; o < 64; o <<= 1) {
    hs += __shfl_xor(hs, o, 64);
    as += __shfl_xor(as, o, 64);
    es += __shfl_xor(es, o, 64);
  }
  if (lane == 0) { redf[wv * 3] = hs; redf[wv * 3 + 1] = as; redf[wv * 3 + 2] = es; }
  __syncthreads();
  hs = redf[0] + redf[3] + redf[6] + redf[9];
  as = redf[1] + redf[4] + redf[7] + redf[10];
  es = redf[2] + redf[5] + redf[8] + redf[11];

  float eflag = (*cnt > 0) ? 1.f : 0.f;
  float w_h = 0.5f * gamma / hs;
  float w_e = 0.5f * (1.f - gamma) * eflag / es;
  float w_a = 0.5f / as;

  // ---- pass 2: A_dyn values + level-0 histogram ----
  float v[16];
#pragma unroll
  for (int c = 0; c < 16; ++c) {
    float eev = __expf(fmaxf(esc * bb[c], 0.f));
    float val = w_h * he[c] + w_e * eev + 0.5f * bb[c] + w_a * ae[c];
    v[c] = val;  // strictly > 0
    atomicAdd(&hist[__float_as_uint(val) >> 20], 1);
  }
  __syncthreads();

  // ---- MSD radix select: digits bits[30:20], [19:9], [8:0] ----
  unsigned kmask = 0, mmask = 0xFFFFu;
  int R = KTOP;
  const int SH[3] = {20, 9, 0};
  const int WD[3] = {2048, 2048, 512};

  for (int lev = 0; lev < 3; ++lev) {
    const int shift = SH[lev], width = WD[lev], bpt = width >> 8;
    if (lev > 0) {
      for (int z = tid; z < width; z += 256) hist[z] = 0;
      __syncthreads();
#pragma unroll
      for (int c = 0; c < 16; ++c)
        if ((mmask >> c) & 1)
          atomicAdd(&hist[(__float_as_uint(v[c]) >> shift) & (width - 1)], 1);
      __syncthreads();
    }
    // suffix scan over buckets (descending value = descending bucket index)
    int s = 0;
    for (int k = 0; k < bpt; ++k) s += hist[tid * bpt + k];
    int x = s;
#pragma unroll
    for (int o = 1; o < 64; o <<= 1) {
      int y = __shfl_down(x, o, 64);
      if (lane + o < 64) x += y;
    }
    if (lane == 0) wtot[wv] = x;
    __syncthreads();
    int S = x;
    for (int w = wv + 1; w < 4; ++w) S += wtot[w];
    int A = S - s;  // count strictly above this thread's bucket group
    if (A < R && S >= R) {  // unique crossing thread
      int cum = A;
      for (int k = bpt - 1; k >= 0; --k) {
        int h = hist[tid * bpt + k];
        cum += h;
        if (cum >= R) { sB = tid * bpt + k; sAbv = cum - h; sNC = h; ccnt = 0; break; }
      }
    }
    __syncthreads();
    int B = sB;
    R -= sAbv;
    int nC = sNC;
#pragma unroll
    for (int c = 0; c < 16; ++c) {
      if ((mmask >> c) & 1) {
        int digit = (int)((__float_as_uint(v[c]) >> shift) & (width - 1));
        if (digit > B) { kmask |= (1u << c); mmask &= ~(1u << c); }
        else if (digit < B) mmask &= ~(1u << c);
      }
    }
    if (nC <= 64) break;  // uniform decision (shared)
  }

  // ---- collect candidates (== prefix) and emit definite keeps (> prefix) ----
#pragma unroll
  for (int c = 0; c < 16; ++c) {
    if ((mmask >> c) & 1) {
      int p = atomicAdd(&ccnt, 1);
      if (p < 64) { candV[p] = v[c]; candJ[p] = c * 256 + tid; }
    }
  }
  float ksum = 0.f;
#pragma unroll
  for (int c = 0; c < 16; ++c) {
    if ((kmask >> c) & 1) {
      int p = atomicAdd(&slotc, 1);
      kidx[i * KTOP + p] = c * 256 + tid;
      kval[i * KTOP + p] = v[c];
      ksum += v[c];
    }
  }
  __syncthreads();
  // thread 0: stable partial selection sort among <=64 candidates, take R
  if (tid == 0) {
    int n = ccnt < 64 ? ccnt : 64;
    float csum = 0.f;
    int base = KTOP - R;
    for (int ss = 0; ss < R; ++ss) {
      int best = ss;
      for (int u = ss + 1; u < n; ++u)
        if (candV[u] > candV[best] ||
            (candV[u] == candV[best] && candJ[u] < candJ[best])) best = u;
      float bv = candV[best]; int bj = candJ[best];
      candV[best] = candV[ss]; candJ[best] = candJ[ss];
      candV[ss] = bv; candJ[ss] = bj;
      kidx[i * KTOP + base + ss] = bj;
      kval[i * KTOP + base + ss] = bv;
      csum += bv;
    }
    sCsum = csum;
  }
  ksum = block_rsumf(ksum, redf);
  if (tid == 0) deg[i] = ksum + sCsum + 1.0f;
}

// ---------------- K3: d^{-1/2} ----------------
__global__ void k_dinv(const float* __restrict__ deg, float* __restrict__ dinv) {
  int i = blockIdx.x * 256 + threadIdx.x;
  dinv[i] = 1.f / sqrtf(deg[i] + EPSF);
}

// ---------------- K4: write normalized sparse output ----------------
__global__ __launch_bounds__(256) void k_write(
    const int* __restrict__ kidx, const float* __restrict__ kval,
    const float* __restrict__ dinv, float* __restrict__ out) {
  const int i = blockIdx.x;
  const int tid = threadIdx.x;
  __shared__ float row[NN];
  float4* r4 = (float4*)row;
#pragma unroll
  for (int c = 0; c < 4; ++c) r4[c * 256 + tid] = make_float4(0.f, 0.f, 0.f, 0.f);
  __syncthreads();
  if (tid < KTOP) {
    int j = kidx[i * KTOP + tid];
    row[j] = kval[i * KTOP + tid];
  }
  __syncthreads();
  float di = dinv[i];
  const float4* dv4 = (const float4*)dinv;
  float4* o4 = (float4*)out;
#pragma unroll
  for (int c = 0; c < 4; ++c) {
    int j4 = c * 256 + tid;
    float4 rv = r4[j4];
    float4 dv = dv4[j4];
    int jb = j4 * 4;
    float4 o;
    o.x = di * (rv.x + ((jb + 0) == i ? 1.f : 0.f)) * dv.x;
    o.y = di * (rv.y + ((jb + 1) == i ? 1.f : 0.f)) * dv.y;
    o.z = di * (rv.z + ((jb + 2) == i ? 1.f : 0.f)) * dv.z;
    o.w = di * (rv.w + ((jb + 3) == i ? 1.f : 0.f)) * dv.w;
    o4[(size_t)i * (NN / 4) + j4] = o;
  }
}

extern "C" void kernel_launch(void* const* d_in, const int* in_sizes, int n_in,
                              void* d_out, int out_size, void* d_ws, size_t ws_size,
                              hipStream_t stream) {
  const float* xh    = (const float*)d_in[0];
  const float* ev    = (const float*)d_in[1];
  const float* base  = (const float*)d_in[2];
  const float* nv1   = (const float*)d_in[3];
  const float* nv2   = (const float*)d_in[4];
  const float* alpha = (const float*)d_in[5];
  float* out = (float*)d_out;

  char* ws = (char*)d_ws;
  int*    cnt   = (int*)ws;                       // 4 B (pad 256)
  float2* featn = (float2*)(ws + 256);            // 32 KB
  float*  sev   = (float*)(ws + 33024);           // 16 KB
  float*  deg   = (float*)(ws + 49408);           // 16 KB
  float*  dinv  = (float*)(ws + 65792);           // 16 KB
  int*    kidx  = (int*)(ws + 82176);             // 320 KB
  float*  kval  = (float*)(ws + 409856);          // 320 KB
  float*  nv2t  = (float*)(ws + 737536);          // 160 KB

  hipMemsetAsync(cnt, 0, 4, stream);
  k_prep<<<NN / 256, 256, 0, stream>>>(xh, ev, nv2, featn, sev, nv2t, cnt);
  k_row<<<NN, 256, 0, stream>>>(base, featn, sev, nv1, nv2t, alpha, cnt, kidx, kval, deg);
  k_dinv<<<NN / 256, 256, 0, stream>>>(deg, dinv);
  k_write<<<NN, 256, 0, stream>>>(kidx, kval, dinv, out);
}